// Round 2
// baseline (3710.166 us; speedup 1.0000x reference)
//
#include <hip/hip_runtime.h>
#include <hip/hip_bf16.h>
#include <math.h>

// Problem constants (match reference)
#define Nn 50000
#define Ee 1600000
#define Gg 64
#define HID 64
#define NHEAD 4
#define CHAN 16

// h = relu(x @ Wn + bn); x: [N,32], Wn: [32,64]
__global__ void k_encode(const float* __restrict__ x, const float* __restrict__ Wn,
                         const float* __restrict__ bn, float* __restrict__ h) {
    __shared__ float sW[32 * 64];
    for (int t = threadIdx.x; t < 32 * 64; t += blockDim.x) sW[t] = Wn[t];
    __syncthreads();
    int lane = threadIdx.x & 63, wv = threadIdx.x >> 6;
    for (int it = 0; it < 16; ++it) {
        int n = blockIdx.x * 64 + it * 4 + wv;
        if (n >= Nn) continue;
        float xv = x[n * 32 + (lane & 31)];
        float acc = bn[lane];
#pragma unroll
        for (int i = 0; i < 32; ++i)
            acc = fmaf(__shfl(xv, i, 32), sW[i * 64 + lane], acc);
        h[n * 64 + lane] = fmaxf(acc, 0.f);
    }
}

// qn/kn/vn = h @ W{q,k,v} + b{q,k,v}
__global__ void k_qkv(const float* __restrict__ h,
                      const float* __restrict__ Wq, const float* __restrict__ bq,
                      const float* __restrict__ Wk, const float* __restrict__ bk,
                      const float* __restrict__ Wv, const float* __restrict__ bv,
                      float* __restrict__ qn, float* __restrict__ kn, float* __restrict__ vn) {
    __shared__ float sq[4096], sk[4096], sv[4096];
    for (int t = threadIdx.x; t < 4096; t += blockDim.x) {
        sq[t] = Wq[t]; sk[t] = Wk[t]; sv[t] = Wv[t];
    }
    __syncthreads();
    int lane = threadIdx.x & 63, wv = threadIdx.x >> 6;
    for (int it = 0; it < 16; ++it) {
        int n = blockIdx.x * 64 + it * 4 + wv;
        if (n >= Nn) continue;
        float hv = h[n * 64 + lane];
        float aq = bq[lane], ak = bk[lane], av = bv[lane];
#pragma unroll
        for (int i = 0; i < 64; ++i) {
            float hi = __shfl(hv, i, 64);
            aq = fmaf(hi, sq[i * 64 + lane], aq);
            ak = fmaf(hi, sk[i * 64 + lane], ak);
            av = fmaf(hi, sv[i * 64 + lane], av);
        }
        qn[n * 64 + lane] = aq;
        kn[n * 64 + lane] = ak;
        vn[n * 64 + lane] = av;
    }
}

// ---- one-time CSR build (counting sort by dst) ----
__global__ void k_hist(const int* __restrict__ ei, int* __restrict__ deg) {
    int e = blockIdx.x * blockDim.x + threadIdx.x;
    if (e < Ee) atomicAdd(&deg[ei[Ee + e]], 1);
}

// single-block exclusive scan of deg[N] -> row_ptr[N+1]
__global__ void k_scan(const int* __restrict__ deg, int* __restrict__ row_ptr) {
    __shared__ int buf[256];
    __shared__ int carry;
    if (threadIdx.x == 0) { carry = 0; row_ptr[0] = 0; }
    __syncthreads();
    for (int base = 0; base < Nn; base += 256) {
        int i = base + threadIdx.x;
        int v = (i < Nn) ? deg[i] : 0;
        buf[threadIdx.x] = v;
        __syncthreads();
#pragma unroll
        for (int off = 1; off < 256; off <<= 1) {
            int t = (threadIdx.x >= off) ? buf[threadIdx.x - off] : 0;
            __syncthreads();
            buf[threadIdx.x] += t;
            __syncthreads();
        }
        int incl = buf[threadIdx.x];
        if (i < Nn) row_ptr[i + 1] = carry + incl;
        __syncthreads();
        if (threadIdx.x == 255) carry += buf[255];
        __syncthreads();
    }
}

__global__ void k_scatter(const int* __restrict__ ei, int* __restrict__ cursor,
                          int* __restrict__ src_perm, int* __restrict__ eperm) {
    int e = blockIdx.x * blockDim.x + threadIdx.x;
    if (e >= Ee) return;
    int dst = ei[Ee + e];
    int pos = atomicAdd(&cursor[dst], 1);
    src_perm[pos] = ei[e];
    eperm[pos] = e;
}

// Fused per-layer edge pass: one wave per dst node.
// Online softmax over in-edges + weighted-V accumulate + skip GEMM + relu + residual.
__global__ void k_edge_fused(const float* __restrict__ qn, const float* __restrict__ kn,
                             const float* __restrict__ vn, const int* __restrict__ row_ptr,
                             const int* __restrict__ src_perm, const int* __restrict__ eperm,
                             const float* __restrict__ ea, const float* __restrict__ We,
                             float* __restrict__ h, const float* __restrict__ Ws,
                             const float* __restrict__ bs) {
    __shared__ float sWe[1024];
    __shared__ float sWs[4096];
    for (int t = threadIdx.x; t < 1024; t += blockDim.x) sWe[t] = We[t];
    for (int t = threadIdx.x; t < 4096; t += blockDim.x) sWs[t] = Ws[t];
    __syncthreads();
    int lane = threadIdx.x & 63, wv = threadIdx.x >> 6;
    for (int n = blockIdx.x * 4 + wv; n < Nn; n += gridDim.x * 4) {
        int beg = row_ptr[n], end = row_ptr[n + 1];
        float q = qn[n * 64 + lane];
        float m = -INFINITY, dsum = 0.f, acc = 0.f;
        for (int idx = beg; idx < end; ++idx) {
            int s = src_perm[idx];
            int ep = eperm[idx];
            float av = ea[ep * 16 + (lane & 15)];
            float ej = 0.f;
#pragma unroll
            for (int i = 0; i < 16; ++i)
                ej = fmaf(__shfl(av, i, 16), sWe[i * 64 + lane], ej);
            float kk = kn[s * 64 + lane] + ej;
            float vv = vn[s * 64 + lane] + ej;
            float t = q * kk;
#pragma unroll
            for (int off = 8; off >= 1; off >>= 1)
                t += __shfl_xor(t, off, 16);
            float a = t * 0.25f;  // 1/sqrt(16)
            float nm = fmaxf(m, a);
            float w = __expf(m - nm);
            float p = __expf(a - nm);
            acc = acc * w + p * vv;
            dsum = dsum * w + p;
            m = nm;
        }
        float hv = h[n * 64 + lane];
        float sk = bs[lane];
#pragma unroll
        for (int i = 0; i < 64; ++i)
            sk = fmaf(__shfl(hv, i, 64), sWs[i * 64 + lane], sk);
        float res = acc / (dsum + 1e-16f);
        h[n * 64 + lane] = hv + fmaxf(res + sk, 0.f);
    }
}

__global__ void k_pool(const float* __restrict__ h, const int* __restrict__ batch,
                       float* __restrict__ pooled, float* __restrict__ cnt) {
    int idx = blockIdx.x * blockDim.x + threadIdx.x;
    if (idx >= Nn * 64) return;
    int n = idx >> 6, j = idx & 63;
    int g = batch[n];
    atomicAdd(&pooled[g * 64 + j], h[idx]);
    if (j == 0) atomicAdd(&cnt[g], 1.f);
}

// out[g] = relu(pooled/cnt @ W1 + b1) @ W2 + b2
__global__ void k_final(const float* __restrict__ pooled, const float* __restrict__ cnt,
                        const float* __restrict__ W1, const float* __restrict__ b1,
                        const float* __restrict__ W2, const float* __restrict__ b2,
                        float* __restrict__ out) {
    int g = blockIdx.x;
    int t = threadIdx.x;  // 64 threads
    __shared__ float sp[64], sh[32];
    float c = fmaxf(cnt[g], 1.f);
    sp[t] = pooled[g * 64 + t] / c;
    __syncthreads();
    if (t < 32) {
        float acc = b1[t];
#pragma unroll
        for (int i = 0; i < 64; ++i) acc = fmaf(sp[i], W1[i * 32 + t], acc);
        sh[t] = fmaxf(acc, 0.f) * W2[t];
    }
    __syncthreads();
    if (t == 0) {
        float s = b2[0];
#pragma unroll
        for (int i = 0; i < 32; ++i) s += sh[i];
        out[g] = s;
    }
}

extern "C" void kernel_launch(void* const* d_in, const int* in_sizes, int n_in,
                              void* d_out, int out_size, void* d_ws, size_t ws_size,
                              hipStream_t stream) {
    const float* x   = (const float*)d_in[0];
    const int*   ei  = (const int*)d_in[1];
    const float* ea  = (const float*)d_in[2];
    const int*   bat = (const int*)d_in[3];
    const float* Wn  = (const float*)d_in[4];
    const float* bn  = (const float*)d_in[5];
    const float* Wq  = (const float*)d_in[6];
    const float* bq  = (const float*)d_in[7];
    const float* Wk  = (const float*)d_in[8];
    const float* bk  = (const float*)d_in[9];
    const float* Wv  = (const float*)d_in[10];
    const float* bv  = (const float*)d_in[11];
    const float* We  = (const float*)d_in[12];
    const float* Wsk = (const float*)d_in[13];
    const float* bs  = (const float*)d_in[14];
    const float* W1  = (const float*)d_in[15];
    const float* b1  = (const float*)d_in[16];
    const float* W2  = (const float*)d_in[17];
    const float* b2  = (const float*)d_in[18];
    float* out = (float*)d_out;

    const size_t NH = (size_t)Nn * 64;
    float* h  = (float*)d_ws;
    float* qn = h + NH;
    float* kn = h + 2 * NH;
    float* vn = h + 3 * NH;
    float* pooled = h + 4 * NH;            // G*64
    float* cnt    = pooled + Gg * 64;      // G
    int* deg      = (int*)(cnt + Gg);      // N (also used as scratch)
    int* row_ptr  = deg + Nn;              // N+1
    int* cursor   = row_ptr + Nn + 1;      // N
    int* src_perm = cursor + Nn;           // E
    int* eperm    = src_perm + Ee;         // E

    dim3 blk(256);
    int nodeBlocks = (Nn + 63) / 64;
    int edgeBlocks = (Ee + 255) / 256;
    int flatBlocks = (Nn * 64 + 255) / 256;

    // one-time CSR build
    hipMemsetAsync(deg, 0, Nn * sizeof(int), stream);
    k_hist<<<edgeBlocks, blk, 0, stream>>>(ei, deg);
    k_scan<<<1, 256, 0, stream>>>(deg, row_ptr);
    hipMemcpyAsync(cursor, row_ptr, Nn * sizeof(int), hipMemcpyDeviceToDevice, stream);
    k_scatter<<<edgeBlocks, blk, 0, stream>>>(ei, cursor, src_perm, eperm);

    k_encode<<<nodeBlocks, blk, 0, stream>>>(x, Wn, bn, h);
    for (int l = 0; l < 3; ++l) {
        k_qkv<<<nodeBlocks, blk, 0, stream>>>(h, Wq + l * 4096, bq + l * 64,
                                              Wk + l * 4096, bk + l * 64,
                                              Wv + l * 4096, bv + l * 64, qn, kn, vn);
        k_edge_fused<<<2048, blk, 0, stream>>>(qn, kn, vn, row_ptr, src_perm, eperm,
                                               ea, We + l * 1024, h, Wsk + l * 4096,
                                               bs + l * 64);
    }
    hipMemsetAsync(pooled, 0, (Gg * 64 + Gg) * sizeof(float), stream);
    k_pool<<<flatBlocks, blk, 0, stream>>>(h, bat, pooled, cnt);
    k_final<<<Gg, 64, 0, stream>>>(pooled, cnt, W1, b1, W2, b2, out);
}

// Round 3
// 2255.017 us; speedup vs baseline: 1.6453x; 1.6453x over previous
//
#include <hip/hip_runtime.h>
#include <math.h>

#define Nn 50000
#define Ee 1600000
#define Gg 64

// ---------------- one-time CSR build ----------------
__global__ void k_hist(const int* __restrict__ ei, int* __restrict__ deg) {
    int e = blockIdx.x * blockDim.x + threadIdx.x;
    if (e < Ee) atomicAdd(&deg[ei[Ee + e]], 1);
}

__global__ void k_scan1(const int* __restrict__ deg, int* __restrict__ row_ptr,
                        int* __restrict__ bsum) {
    __shared__ int buf[256];
    int i = blockIdx.x * 256 + threadIdx.x;
    int v = (i < Nn) ? deg[i] : 0;
    buf[threadIdx.x] = v;
    __syncthreads();
    for (int off = 1; off < 256; off <<= 1) {
        int t = (threadIdx.x >= off) ? buf[threadIdx.x - off] : 0;
        __syncthreads();
        buf[threadIdx.x] += t;
        __syncthreads();
    }
    if (i < Nn) row_ptr[i + 1] = buf[threadIdx.x];  // block-local inclusive
    if (threadIdx.x == 255) bsum[blockIdx.x] = buf[255];
}

__global__ void k_scan2(int* __restrict__ bsum, int nb) {
    __shared__ int buf[256];
    int v = (threadIdx.x < nb) ? bsum[threadIdx.x] : 0;
    buf[threadIdx.x] = v;
    __syncthreads();
    for (int off = 1; off < 256; off <<= 1) {
        int t = (threadIdx.x >= off) ? buf[threadIdx.x - off] : 0;
        __syncthreads();
        buf[threadIdx.x] += t;
        __syncthreads();
    }
    if (threadIdx.x < nb) bsum[threadIdx.x] = buf[threadIdx.x];  // inclusive
}

__global__ void k_scan3(int* __restrict__ row_ptr, const int* __restrict__ bsum) {
    int i = blockIdx.x * 256 + threadIdx.x;  // i in [0, Nn]
    if (i > Nn) return;
    if (i == 0) { row_ptr[0] = 0; return; }
    int b = (i - 1) >> 8;
    if (b > 0) row_ptr[i] += bsum[b - 1];
}

__global__ void k_scatter(const int* __restrict__ ei, int* __restrict__ cursor,
                          int* __restrict__ src_perm, int* __restrict__ eperm,
                          int* __restrict__ dst_sorted) {
    int e = blockIdx.x * blockDim.x + threadIdx.x;
    if (e >= Ee) return;
    int dst = ei[Ee + e];
    int pos = atomicAdd(&cursor[dst], 1);
    src_perm[pos] = ei[e];
    eperm[pos] = e;
    dst_sorted[pos] = dst;
}

__global__ void k_gbound(const int* __restrict__ batch, int* __restrict__ gstart) {
    int n = blockIdx.x * blockDim.x + threadIdx.x;
    if (n >= Nn) return;
    int b = batch[n];
    if (n == 0) { for (int g = 0; g <= b; ++g) gstart[g] = 0; }
    else { int bp = batch[n - 1]; for (int g = bp + 1; g <= b; ++g) gstart[g] = n; }
    if (n == Nn - 1) { for (int g = b + 1; g <= Gg; ++g) gstart[g] = Nn; }
}

// ---------------- node kernels ----------------
// h = relu(x @ Wn + bn); broadcast reads, no shfl
__global__ void k_encode(const float* __restrict__ x, const float* __restrict__ Wn,
                         const float* __restrict__ bn, float* __restrict__ h) {
    int lane = threadIdx.x & 63, wv = threadIdx.x >> 6;
    for (int it = 0; it < 16; ++it) {
        int n = blockIdx.x * 64 + wv * 16 + it;
        if (n >= Nn) continue;
        float acc = bn[lane];
#pragma unroll 8
        for (int i = 0; i < 32; ++i)
            acc = fmaf(x[n * 32 + i], Wn[i * 64 + lane], acc);
        h[(size_t)n * 64 + lane] = fmaxf(acc, 0.f);
    }
}

// Wqm[j][l'=(h,i)] = sum_c Wq[j][h*16+c] * We[i][h*16+c];  bqm likewise from bq
__global__ void k_wqm(const float* __restrict__ Wq, const float* __restrict__ bq,
                      const float* __restrict__ We, float* __restrict__ Wqm,
                      float* __restrict__ bqm) {
    for (int o = threadIdx.x; o < 64 * 64; o += 256) {
        int j = o >> 6, lp = o & 63, hh = lp >> 4, ii = lp & 15;
        float acc = 0.f;
#pragma unroll
        for (int c = 0; c < 16; ++c)
            acc += Wq[j * 64 + hh * 16 + c] * We[ii * 64 + hh * 16 + c];
        Wqm[o] = acc;
    }
    if (threadIdx.x < 64) {
        int hh = threadIdx.x >> 4, ii = threadIdx.x & 15;
        float acc = 0.f;
#pragma unroll
        for (int c = 0; c < 16; ++c)
            acc += bq[hh * 16 + c] * We[ii * 64 + hh * 16 + c];
        bqm[threadIdx.x] = acc;
    }
}

// qn,kn,vn = h@W+b ; tq = h@Wqm+bqm ; sn = h@Ws+bs  (5 accumulators, one h stream)
__global__ void k_qkvt(const float* __restrict__ h,
                       const float* __restrict__ Wq, const float* __restrict__ bq,
                       const float* __restrict__ Wk, const float* __restrict__ bk,
                       const float* __restrict__ Wv, const float* __restrict__ bv,
                       const float* __restrict__ Wqm, const float* __restrict__ bqm,
                       const float* __restrict__ Ws, const float* __restrict__ bs,
                       float* __restrict__ qn, float* __restrict__ kn,
                       float* __restrict__ vn, float* __restrict__ tq,
                       float* __restrict__ sn) {
    int lane = threadIdx.x & 63, wv = threadIdx.x >> 6;
    for (int it = 0; it < 16; ++it) {
        int n = blockIdx.x * 64 + wv * 16 + it;
        if (n >= Nn) continue;
        float aq = bq[lane], ak = bk[lane], av = bv[lane], at = bqm[lane], as_ = bs[lane];
#pragma unroll 8
        for (int i = 0; i < 64; ++i) {
            float hi = h[(size_t)n * 64 + i];
            aq = fmaf(hi, Wq[i * 64 + lane], aq);
            ak = fmaf(hi, Wk[i * 64 + lane], ak);
            av = fmaf(hi, Wv[i * 64 + lane], av);
            at = fmaf(hi, Wqm[i * 64 + lane], at);
            as_ = fmaf(hi, Ws[i * 64 + lane], as_);
        }
        size_t o = (size_t)n * 64 + lane;
        qn[o] = aq; kn[o] = ak; vn[o] = av; tq[o] = at; sn[o] = as_;
    }
}

// edge-parallel, CSR order: alpha[idx][h] = 0.25*(q[d]·k[s] + ea[e]·tq[d])
__global__ void k_alpha(const float* __restrict__ qn, const float* __restrict__ kn,
                        const float* __restrict__ tq, const int* __restrict__ src_perm,
                        const int* __restrict__ dst_sorted, const int* __restrict__ eperm,
                        const float* __restrict__ ea, float* __restrict__ alpha) {
    __shared__ float ea_s[64 * 16];
    __shared__ float al_s[64 * 4];
    int base = blockIdx.x * 64;
    {   // stage 64 edges' ea rows (float4-coalesced gather)
        int t = threadIdx.x;
        int idx = base + (t >> 2);
        if (idx < Ee) {
            int e = eperm[idx];
            ((float4*)ea_s)[t] = ((const float4*)(ea + (size_t)e * 16))[t & 3];
        }
    }
    __syncthreads();
    int lane = threadIdx.x & 63, wv = threadIdx.x >> 6;
    int hh = lane >> 4, cc = lane & 15;
    for (int it = 0; it < 16; ++it) {
        int el = wv * 16 + it;
        int idx = base + el;
        if (idx < Ee) {
            int s = src_perm[idx], d = dst_sorted[idx];
            float q = qn[(size_t)d * 64 + lane];
            float k = kn[(size_t)s * 64 + lane];
            float t = tq[(size_t)d * 64 + lane];
            float part = q * k + ea_s[el * 16 + cc] * t;
            part += __shfl_xor(part, 1, 16);
            part += __shfl_xor(part, 2, 16);
            part += __shfl_xor(part, 4, 16);
            part += __shfl_xor(part, 8, 16);
            if (cc == 0) al_s[el * 4 + hh] = part * 0.25f;
        }
    }
    __syncthreads();
    {
        long gi = (long)base * 4 + threadIdx.x;
        if (gi < (long)Ee * 4) alpha[gi] = al_s[threadIdx.x];
    }
}

// node-parallel aggregation: max sweep + 4-way-unrolled weighted sums, then
// (acce)@We transform + skip + relu + residual. No atomics.
__global__ void k_agg(float* __restrict__ h, const float* __restrict__ vn,
                      const float* __restrict__ sn, const float* __restrict__ alpha,
                      const int* __restrict__ row_ptr, const int* __restrict__ src_perm,
                      const int* __restrict__ eperm, const float* __restrict__ ea,
                      const float* __restrict__ We) {
    __shared__ float sWe[1024];
    __shared__ float tile[4][64];
    for (int t = threadIdx.x; t < 1024; t += 256) sWe[t] = We[t];
    __syncthreads();
    int lane = threadIdx.x & 63, wv = threadIdx.x >> 6;
    int hh = lane >> 4, cc = lane & 15;
    int n = blockIdx.x * 4 + wv;
    if (n >= Nn) return;
    int beg = row_ptr[n], end = row_ptr[n + 1];
    // sweep 1: per-head max (coalesced: 64 lanes cover 16 edges x 4 heads)
    float vm = -INFINITY;
    for (int b = beg; b < end; b += 16) {
        int j = b + cc;
        if (j < end) vm = fmaxf(vm, alpha[(size_t)j * 4 + hh]);
    }
    vm = fmaxf(vm, __shfl_xor(vm, 1, 16));
    vm = fmaxf(vm, __shfl_xor(vm, 2, 16));
    vm = fmaxf(vm, __shfl_xor(vm, 4, 16));
    vm = fmaxf(vm, __shfl_xor(vm, 8, 16));
    // sweep 2: weighted accumulation, 4 edges in flight
    float accv = 0.f, acce = 0.f, accd = 0.f;
    int idx = beg;
    for (; idx + 4 <= end; idx += 4) {
        int s0 = src_perm[idx], s1 = src_perm[idx + 1], s2 = src_perm[idx + 2], s3 = src_perm[idx + 3];
        int e0 = eperm[idx], e1 = eperm[idx + 1], e2 = eperm[idx + 2], e3 = eperm[idx + 3];
        float a0 = alpha[(size_t)idx * 4 + hh], a1 = alpha[(size_t)(idx + 1) * 4 + hh];
        float a2 = alpha[(size_t)(idx + 2) * 4 + hh], a3 = alpha[(size_t)(idx + 3) * 4 + hh];
        float v0 = vn[(size_t)s0 * 64 + lane], v1 = vn[(size_t)s1 * 64 + lane];
        float v2 = vn[(size_t)s2 * 64 + lane], v3 = vn[(size_t)s3 * 64 + lane];
        float x0 = ea[(size_t)e0 * 16 + cc], x1 = ea[(size_t)e1 * 16 + cc];
        float x2 = ea[(size_t)e2 * 16 + cc], x3 = ea[(size_t)e3 * 16 + cc];
        float p0 = __expf(a0 - vm), p1 = __expf(a1 - vm);
        float p2 = __expf(a2 - vm), p3 = __expf(a3 - vm);
        accd += (p0 + p1) + (p2 + p3);
        accv = fmaf(p0, v0, fmaf(p1, v1, fmaf(p2, v2, fmaf(p3, v3, accv))));
        acce = fmaf(p0, x0, fmaf(p1, x1, fmaf(p2, x2, fmaf(p3, x3, acce))));
    }
    for (; idx < end; ++idx) {
        int s0 = src_perm[idx], e0 = eperm[idx];
        float p0 = __expf(alpha[(size_t)idx * 4 + hh] - vm);
        accd += p0;
        accv = fmaf(p0, vn[(size_t)s0 * 64 + lane], accv);
        acce = fmaf(p0, ea[(size_t)e0 * 16 + cc], acce);
    }
    float inv = 1.f / (accd + 1e-16f);
    tile[wv][lane] = acce * inv;  // (h,i) layout, wave-local LDS (no barrier needed)
    float re = 0.f;
#pragma unroll
    for (int i = 0; i < 16; ++i)
        re = fmaf(tile[wv][hh * 16 + i], sWe[i * 64 + lane], re);
    size_t o = (size_t)n * 64 + lane;
    float hv = h[o];
    h[o] = hv + fmaxf(accv * inv + re + sn[o], 0.f);
}

// mean-pool per group (batch sorted -> boundaries) + fused MLP head
__global__ void k_pool(const float* __restrict__ h, const int* __restrict__ gstart,
                       const float* __restrict__ W1, const float* __restrict__ b1,
                       const float* __restrict__ W2, const float* __restrict__ b2,
                       float* __restrict__ out) {
    int g = blockIdx.x;
    int lane = threadIdx.x & 63, wv = threadIdx.x >> 6;
    int beg = gstart[g], end = gstart[g + 1];
    __shared__ float red[4][64];
    __shared__ float sp[64];
    __shared__ float sh[32];
    float acc = 0.f;
    for (int n = beg + wv; n < end; n += 4) acc += h[(size_t)n * 64 + lane];
    red[wv][lane] = acc;
    __syncthreads();
    if (threadIdx.x < 64) {
        float c = fmaxf((float)(end - beg), 1.f);
        sp[lane] = (red[0][lane] + red[1][lane] + red[2][lane] + red[3][lane]) / c;
    }
    __syncthreads();
    if (threadIdx.x < 32) {
        int t = threadIdx.x;
        float a = b1[t];
#pragma unroll
        for (int i = 0; i < 64; ++i) a = fmaf(sp[i], W1[i * 32 + t], a);
        sh[t] = fmaxf(a, 0.f) * W2[t];
    }
    __syncthreads();
    if (threadIdx.x == 0) {
        float s = b2[0];
#pragma unroll
        for (int i = 0; i < 32; ++i) s += sh[i];
        out[g] = s;
    }
}

extern "C" void kernel_launch(void* const* d_in, const int* in_sizes, int n_in,
                              void* d_out, int out_size, void* d_ws, size_t ws_size,
                              hipStream_t stream) {
    const float* x   = (const float*)d_in[0];
    const int*   ei  = (const int*)d_in[1];
    const float* ea  = (const float*)d_in[2];
    const int*   bat = (const int*)d_in[3];
    const float* Wn  = (const float*)d_in[4];
    const float* bn  = (const float*)d_in[5];
    const float* Wq  = (const float*)d_in[6];
    const float* bq  = (const float*)d_in[7];
    const float* Wk  = (const float*)d_in[8];
    const float* bk  = (const float*)d_in[9];
    const float* Wv  = (const float*)d_in[10];
    const float* bv  = (const float*)d_in[11];
    const float* We  = (const float*)d_in[12];
    const float* Wsk = (const float*)d_in[13];
    const float* bs  = (const float*)d_in[14];
    const float* W1  = (const float*)d_in[15];
    const float* b1  = (const float*)d_in[16];
    const float* W2  = (const float*)d_in[17];
    const float* b2  = (const float*)d_in[18];
    float* out = (float*)d_out;

    const size_t NH = (size_t)Nn * 64;
    float* h    = (float*)d_ws;
    float* qn   = h + NH;
    float* kn   = h + 2 * NH;
    float* vn   = h + 3 * NH;
    float* tq   = h + 4 * NH;
    float* sn   = h + 5 * NH;
    float* alpha = h + 6 * NH;                 // E*4
    float* Wqm  = alpha + (size_t)Ee * 4;      // 4096
    float* bqm  = Wqm + 4096;                  // 64
    int* deg       = (int*)(bqm + 64);         // N
    int* row_ptr   = deg + Nn;                 // N+1
    int* cursor    = row_ptr + Nn + 1;         // N
    int* src_perm  = cursor + Nn;              // E
    int* eperm     = src_perm + Ee;            // E
    int* dst_sorted = eperm + Ee;              // E
    int* bsum      = dst_sorted + Ee;          // 256
    int* gstart    = bsum + 256;               // G+1

    const int NB = 196;  // ceil(50000/256)
    hipMemsetAsync(deg, 0, Nn * sizeof(int), stream);
    k_hist<<<(Ee + 255) / 256, 256, 0, stream>>>(ei, deg);
    k_scan1<<<NB, 256, 0, stream>>>(deg, row_ptr, bsum);
    k_scan2<<<1, 256, 0, stream>>>(bsum, NB);
    k_scan3<<<(Nn + 256) / 256, 256, 0, stream>>>(row_ptr, bsum);
    hipMemcpyAsync(cursor, row_ptr, Nn * sizeof(int), hipMemcpyDeviceToDevice, stream);
    k_scatter<<<(Ee + 255) / 256, 256, 0, stream>>>(ei, cursor, src_perm, eperm, dst_sorted);
    k_gbound<<<(Nn + 255) / 256, 256, 0, stream>>>(bat, gstart);

    int nodeBlocks = (Nn + 63) / 64;
    k_encode<<<nodeBlocks, 256, 0, stream>>>(x, Wn, bn, h);
    for (int l = 0; l < 3; ++l) {
        k_wqm<<<1, 256, 0, stream>>>(Wq + l * 4096, bq + l * 64, We + l * 1024, Wqm, bqm);
        k_qkvt<<<nodeBlocks, 256, 0, stream>>>(h, Wq + l * 4096, bq + l * 64,
                                               Wk + l * 4096, bk + l * 64,
                                               Wv + l * 4096, bv + l * 64,
                                               Wqm, bqm, Wsk + l * 4096, bs + l * 64,
                                               qn, kn, vn, tq, sn);
        k_alpha<<<(Ee + 63) / 64, 256, 0, stream>>>(qn, kn, tq, src_perm, dst_sorted,
                                                    eperm, ea, alpha);
        k_agg<<<(Nn + 3) / 4, 256, 0, stream>>>(h, vn, sn, alpha, row_ptr, src_perm,
                                                eperm, ea, We + l * 1024);
    }
    k_pool<<<Gg, 256, 0, stream>>>(h, gstart, W1, b1, W2, b2, out);
}